// Round 1
// baseline (514.325 us; speedup 1.0000x reference)
//
#include <hip/hip_runtime.h>

// VQ-VAE vector quantize + losses, MI355X fp32.
// T=8192 rows (b*h*w), N_E=16384 codes, D=32.
// ws layout (floats): embn[524288] ses[16384] zf[262144] a0[8192]
//   pm[262144] pZ[262144] pW[262144] pidx[262144(int)]
//   lse[8192] idxo[8192(int)] avg[16384] scal[2]   -> ~7.6 MB total

#define N_E 16384
#define ED 32
#define T 8192
#define NSPLIT 32
#define NPER (N_E / NSPLIT) // 512
#define TCH 16
#define TPER (T / TCH)      // 512

__device__ __forceinline__ float fexp2(float x) { return __builtin_amdgcn_exp2f(x); }
__device__ __forceinline__ float flog2(float x) { return __builtin_amdgcn_logf(x); }
#define L2E 1.4426950408889634f
#define LN2 0.6931471805599453f

// --- K0: normalize embedding rows, ses[n] = -100 * sum(embn^2) ---
__global__ __launch_bounds__(256) void k_norm_emb(const float* __restrict__ emb,
    float* __restrict__ embn, float* __restrict__ ses) {
  int n = blockIdx.x * 256 + threadIdx.x;
  const float* r = emb + (size_t)n * ED;
  float v[ED]; float s = 0.f;
#pragma unroll
  for (int k = 0; k < ED; ++k) { v[k] = r[k]; s = fmaf(v[k], v[k], s); }
  float inv = 1.0f / fmaxf(sqrtf(s), 1e-12f);
  float s2 = 0.f;
  float* o = embn + (size_t)n * ED;
#pragma unroll
  for (int k = 0; k < ED; ++k) { float w = v[k] * inv; o[k] = w; s2 = fmaf(w, w, s2); }
  ses[n] = -100.0f * s2;
}

// --- K1: transpose+normalize z -> zf (T x 32 row-major), a0[t] = -100*sum(zf^2) ---
__global__ __launch_bounds__(256) void k_norm_z(const float* __restrict__ z,
    float* __restrict__ zf, float* __restrict__ a0) {
  int t = blockIdx.x * 256 + threadIdx.x;
  int b = t >> 8, hw = t & 255;
  const float* base = z + (size_t)b * (ED * 256) + hw;
  float v[ED]; float s = 0.f;
#pragma unroll
  for (int k = 0; k < ED; ++k) { v[k] = base[k * 256]; s = fmaf(v[k], v[k], s); }
  float inv = 1.0f / fmaxf(sqrtf(s), 1e-12f);
  float s2 = 0.f;
  float* o = zf + (size_t)t * ED;
#pragma unroll
  for (int k = 0; k < ED; ++k) { float w = v[k] * inv; o[k] = w; s2 = fmaf(w, w, s2); }
  a0[t] = -100.0f * s2;
}

// --- P1: lane owns row t; sweep an n-split; online softmax over fa = -100*d
//     plus running argmax-fa (== argmin d, first index on ties). ---
__global__ __launch_bounds__(256) void k_p1(const float* __restrict__ embn,
    const float* __restrict__ ses, const float* __restrict__ zf,
    const float* __restrict__ a0, float* __restrict__ pm, float* __restrict__ pZ,
    float* __restrict__ pW, int* __restrict__ pidx) {
  const int t = blockIdx.x * 256 + threadIdx.x;
  const int s = blockIdx.y;
  const int nbase = s * NPER;
  float zr[ED];
#pragma unroll
  for (int k = 0; k < ED; ++k) zr[k] = zf[(size_t)t * ED + k];
  const float a0t = a0[t];
  float m = -1e30f, Z = 0.f, W = 0.f;
  int bidx = nbase;
  for (int i = 0; i < NPER; ++i) {
    const int n = nbase + i;
    const float4* e4 = (const float4*)(embn + (size_t)n * ED);
    float acc0 = 0.f, acc1 = 0.f, acc2 = 0.f, acc3 = 0.f;
#pragma unroll
    for (int j = 0; j < 8; j += 4) {
      float4 q0 = e4[j + 0];
      acc0 = fmaf(q0.x, zr[4 * j + 0], acc0);  acc0 = fmaf(q0.y, zr[4 * j + 1], acc0);
      acc0 = fmaf(q0.z, zr[4 * j + 2], acc0);  acc0 = fmaf(q0.w, zr[4 * j + 3], acc0);
      float4 q1 = e4[j + 1];
      acc1 = fmaf(q1.x, zr[4 * j + 4], acc1);  acc1 = fmaf(q1.y, zr[4 * j + 5], acc1);
      acc1 = fmaf(q1.z, zr[4 * j + 6], acc1);  acc1 = fmaf(q1.w, zr[4 * j + 7], acc1);
      float4 q2 = e4[j + 2];
      acc2 = fmaf(q2.x, zr[4 * j + 8], acc2);  acc2 = fmaf(q2.y, zr[4 * j + 9], acc2);
      acc2 = fmaf(q2.z, zr[4 * j + 10], acc2); acc2 = fmaf(q2.w, zr[4 * j + 11], acc2);
      float4 q3 = e4[j + 3];
      acc3 = fmaf(q3.x, zr[4 * j + 12], acc3); acc3 = fmaf(q3.y, zr[4 * j + 13], acc3);
      acc3 = fmaf(q3.z, zr[4 * j + 14], acc3); acc3 = fmaf(q3.w, zr[4 * j + 15], acc3);
    }
    float dot = (acc0 + acc1) + (acc2 + acc3);
    float fa = fmaf(200.f, dot, a0t + ses[n]);
    if (fa > m) {  // new running max: rescale accumulated Z/W
      float sc = fexp2((m - fa) * L2E);
      Z *= sc; W *= sc; m = fa; bidx = n;
    }
    float ee = fexp2((fa - m) * L2E);
    Z += ee;
    W = fmaf(ee, fa, W);
  }
  const int p = s * T + t;
  pm[p] = m; pZ[p] = Z; pW[p] = W; pidx[p] = bidx;
}

// --- K3: merge the NSPLIT partials per row, produce lse[t], idx[t];
//     accumulate sum(p log p) and vq sum-of-squares. ---
__global__ __launch_bounds__(256) void k_merge(const float* __restrict__ pm,
    const float* __restrict__ pZ, const float* __restrict__ pW,
    const int* __restrict__ pidx, const float* __restrict__ zf,
    const float* __restrict__ embn, float* __restrict__ lse,
    int* __restrict__ idxo, float* __restrict__ scal) {
  const int t = blockIdx.x * 256 + threadIdx.x;
  float m = -1e30f; int bi = 0;
  for (int s = 0; s < NSPLIT; ++s) {
    float ms = pm[s * T + t];
    if (ms > m) { m = ms; bi = pidx[s * T + t]; }  // strict > keeps lowest n on ties
  }
  float Z = 0.f, W = 0.f;
  for (int s = 0; s < NSPLIT; ++s) {
    float sc = fexp2((pm[s * T + t] - m) * L2E);
    Z = fmaf(pZ[s * T + t], sc, Z);
    W = fmaf(pW[s * T + t], sc, W);
  }
  float lset = m + flog2(Z) * LN2;     // ln-sum-exp
  float plogp = W / Z - lset;          // sum_n p*log p  (<=0)
  lse[t] = lset; idxo[t] = bi;
  float ss = 0.f;
  const float* zq = embn + (size_t)bi * ED;
  const float* zr = zf + (size_t)t * ED;
#pragma unroll
  for (int k = 0; k < ED; ++k) { float df = zq[k] - zr[k]; ss = fmaf(df, df, ss); }
  __shared__ float red1[256], red2[256];
  red1[threadIdx.x] = plogp; red2[threadIdx.x] = ss;
  __syncthreads();
  for (int st = 128; st > 0; st >>= 1) {
    if (threadIdx.x < st) {
      red1[threadIdx.x] += red1[threadIdx.x + st];
      red2[threadIdx.x] += red2[threadIdx.x + st];
    }
    __syncthreads();
  }
  if (threadIdx.x == 0) { atomicAdd(&scal[0], red1[0]); atomicAdd(&scal[1], red2[0]); }
}

// --- P3: lane owns code n; sweep a t-chunk; accumulate avg_probs[n]. ---
__global__ __launch_bounds__(256) void k_avg(const float* __restrict__ embn,
    const float* __restrict__ ses, const float* __restrict__ zf,
    const float* __restrict__ a0, const float* __restrict__ lse,
    float* __restrict__ avg) {
  const int n = blockIdx.x * 256 + threadIdx.x;
  const int tbase = blockIdx.y * TPER;
  float er[ED];
#pragma unroll
  for (int k = 0; k < ED; ++k) er[k] = embn[(size_t)n * ED + k];
  const float sesn = ses[n];
  float acc = 0.f;
  for (int i = 0; i < TPER; ++i) {
    const int t = tbase + i;
    const float4* z4 = (const float4*)(zf + (size_t)t * ED);
    float a0_ = 0.f, a1_ = 0.f, a2_ = 0.f, a3_ = 0.f;
#pragma unroll
    for (int j = 0; j < 8; j += 4) {
      float4 q0 = z4[j + 0];
      a0_ = fmaf(q0.x, er[4 * j + 0], a0_);  a0_ = fmaf(q0.y, er[4 * j + 1], a0_);
      a0_ = fmaf(q0.z, er[4 * j + 2], a0_);  a0_ = fmaf(q0.w, er[4 * j + 3], a0_);
      float4 q1 = z4[j + 1];
      a1_ = fmaf(q1.x, er[4 * j + 4], a1_);  a1_ = fmaf(q1.y, er[4 * j + 5], a1_);
      a1_ = fmaf(q1.z, er[4 * j + 6], a1_);  a1_ = fmaf(q1.w, er[4 * j + 7], a1_);
      float4 q2 = z4[j + 2];
      a2_ = fmaf(q2.x, er[4 * j + 8], a2_);  a2_ = fmaf(q2.y, er[4 * j + 9], a2_);
      a2_ = fmaf(q2.z, er[4 * j + 10], a2_); a2_ = fmaf(q2.w, er[4 * j + 11], a2_);
      float4 q3 = z4[j + 3];
      a3_ = fmaf(q3.x, er[4 * j + 12], a3_); a3_ = fmaf(q3.y, er[4 * j + 13], a3_);
      a3_ = fmaf(q3.z, er[4 * j + 14], a3_); a3_ = fmaf(q3.w, er[4 * j + 15], a3_);
    }
    float dot = (a0_ + a1_) + (a2_ + a3_);
    float fa = fmaf(200.f, dot, sesn + a0[t]);
    float dl = fa - lse[t];
    if (dl > -75.f) acc += fexp2(dl * L2E);  // p < e^-75 underflows in ref too
  }
  atomicAdd(&avg[n], acc);
}

// --- K4: straight-through output, back to (b,c,h,w). out = zb + (z_q - zb). ---
__global__ __launch_bounds__(256) void k_out(const float* __restrict__ zf,
    const float* __restrict__ embn, const int* __restrict__ idxo,
    float* __restrict__ out) {
  int o = blockIdx.x * 256 + threadIdx.x;
  int c = (o >> 8) & 31;
  int t = ((o >> 13) << 8) | (o & 255);
  float zv = zf[(size_t)t * ED + c];
  float qv = embn[(size_t)idxo[t] * ED + c];
  out[o] = zv + (qv - zv);  // match fp32 op order of zb + stopgrad(z_q - zb)
}

// --- K5: avg entropy reduction + final scalars. ---
__global__ __launch_bounds__(256) void k_final(const float* __restrict__ avg,
    const float* __restrict__ scal, float* __restrict__ out) {
  float s = 0.f;
  for (int i = threadIdx.x; i < N_E; i += 256) {
    float a = avg[i] * (1.0f / T);
    s += a * (flog2(a + 1e-5f) * LN2);  // a==0 contributes exactly 0
  }
  __shared__ float red[256];
  red[threadIdx.x] = s;
  __syncthreads();
  for (int st = 128; st > 0; st >>= 1) {
    if (threadIdx.x < st) red[threadIdx.x] += red[threadIdx.x + st];
    __syncthreads();
  }
  if (threadIdx.x == 0) {
    float avg_entropy = -red[0];
    float sample_entropy = -scal[0] * (1.0f / T);
    float vq = scal[1] * (1.0f / (T * ED));
    out[T * ED + 0] = vq;
    out[T * ED + 1] = 0.25f * vq;
    out[T * ED + 2] = 0.1f * (sample_entropy - avg_entropy);
  }
}

extern "C" void kernel_launch(void* const* d_in, const int* in_sizes, int n_in,
                              void* d_out, int out_size, void* d_ws, size_t ws_size,
                              hipStream_t stream) {
  const float* z = (const float*)d_in[0];
  const float* emb = (const float*)d_in[1];
  float* out = (float*)d_out;
  float* w = (float*)d_ws;

  float* embn = w;                       // 524288
  float* ses = embn + 524288;            // 16384
  float* zf = ses + 16384;               // 262144
  float* a0 = zf + 262144;               // 8192
  float* pm = a0 + 8192;                 // 262144
  float* pZ = pm + 262144;               // 262144
  float* pW = pZ + 262144;               // 262144
  int* pidx = (int*)(pW + 262144);       // 262144
  float* lse = (float*)(pidx + 262144);  // 8192
  int* idxo = (int*)(lse + 8192);        // 8192
  float* avg = (float*)(idxo + 8192);    // 16384
  float* scal = avg + 16384;             // 2

  // avg + scal must start at 0 (ws is poisoned 0xAA before every call)
  hipMemsetAsync(avg, 0, (16384 + 2) * sizeof(float), stream);

  k_norm_emb<<<64, 256, 0, stream>>>(emb, embn, ses);
  k_norm_z<<<32, 256, 0, stream>>>(z, zf, a0);
  k_p1<<<dim3(32, NSPLIT), 256, 0, stream>>>(embn, ses, zf, a0, pm, pZ, pW, pidx);
  k_merge<<<32, 256, 0, stream>>>(pm, pZ, pW, pidx, zf, embn, lse, idxo, scal);
  k_avg<<<dim3(N_E / 256, TCH), 256, 0, stream>>>(embn, ses, zf, a0, lse, avg);
  k_out<<<1024, 256, 0, stream>>>(zf, embn, idxo, out);
  k_final<<<1, 256, 0, stream>>>(avg, scal, out);
}